// Round 1
// baseline (5470.583 us; speedup 1.0000x reference)
//
#include <hip/hip_runtime.h>

// DA-RNN fused kernel: one block per batch element, encoder + decoder + head.
// B=1024, T=100, M=H=P=128, C=32. All global I/O fp32; LDS slabs bf16.

typedef unsigned int  u32;
typedef unsigned short u16;

#define T_ 100
#define C_ 32

__device__ __forceinline__ float bf2f(u16 u) {
  union { u32 i; float f; } v; v.i = ((u32)u) << 16; return v.f;
}
__device__ __forceinline__ u16 f2bf(float f) {
  union { float f; u32 i; } v; v.f = f;
  u32 r = v.i + 0x7fffu + ((v.i >> 16) & 1u);   // round-to-nearest-even
  return (u16)(r >> 16);
}
__device__ __forceinline__ void unpk(u32 p, float& lo, float& hi) {
  union { u32 i; float f; } a, b;
  a.i = p << 16; b.i = p & 0xffff0000u;
  lo = a.f; hi = b.f;
}
__device__ __forceinline__ u32 pk2(float a, float b) {
  return ((u32)f2bf(b) << 16) | (u32)f2bf(a);
}

#if __has_builtin(__builtin_amdgcn_rcpf)
__device__ __forceinline__ float rcpf_(float x){ return __builtin_amdgcn_rcpf(x); }
#else
__device__ __forceinline__ float rcpf_(float x){ return 1.0f / x; }
#endif
__device__ __forceinline__ float sigm(float x){ return rcpf_(1.0f + __expf(-x)); }
__device__ __forceinline__ float tanh_(float x){
  // 1 - 2/(1+e^{2x}); exact at +-inf, ~1e-7 abs error in the tiny-signal regime here
  return 1.0f - 2.0f * rcpf_(1.0f + __expf(2.0f * x));
}

__device__ __forceinline__ float wsum(float v){
  #pragma unroll
  for (int o = 32; o; o >>= 1) v += __shfl_xor(v, o, 64);
  return v;
}
__device__ __forceinline__ float wmax(float v){
  #pragma unroll
  for (int o = 32; o; o >>= 1) v = fmaxf(v, __shfl_xor(v, o, 64));
  return v;
}

__global__ void __launch_bounds__(512)
darnn_fused(const float* __restrict__ X,
            const float* __restrict__ eWih, const float* __restrict__ eWhh,
            const float* __restrict__ ebih, const float* __restrict__ ebhh,
            const float* __restrict__ eAw,  const float* __restrict__ eAb,
            const float* __restrict__ dW1,  const float* __restrict__ db1,
            const float* __restrict__ dW2,  const float* __restrict__ db2,
            const float* __restrict__ dWih, const float* __restrict__ dWhh,
            const float* __restrict__ dbih, const float* __restrict__ dbhh,
            const float* __restrict__ fcW,  const float* __restrict__ fcb,
            const float* __restrict__ fcfW, const float* __restrict__ fcfb,
            float* __restrict__ out)
{
  // LDS: 25600+25600+2048+512*5+64 = ~58.1 KB (< 64 KB/WG)
  __shared__ __align__(16) u16   sxh[12800];   // phase-enc: x_tilde bf16; phase-dec: E1 bf16
  __shared__ __align__(16) u16   sxe[12800];   // X_enc bf16
  __shared__ __align__(16) float sg[512];      // gates
  __shared__ __align__(16) float sh[128];      // h (enc) / d (dec)
  __shared__ __align__(16) float sc[128];      // c
  __shared__ __align__(16) float su[128];      // alpha (prologue) / u (dec)
  __shared__ __align__(16) float spart[512];   // u partials / ctx partials
  __shared__ __align__(16) float sscore[128];  // scores -> beta
  __shared__ __align__(16) float sctx[128];    // ctx
  __shared__ float sred[8];

  const int tid  = threadIdx.x;
  const int lane = tid & 63;
  const int wv   = tid >> 6;
  const int b    = blockIdx.x;
  const int hh   = tid & 127;  // split-role h index
  const int qq   = tid >> 7;   // 0..3

  // ================= encoder prologue =================
  {
    const float* Xb = X + (size_t)b * (T_ * 128);
    #pragma unroll
    for (int r = 0; r < 25; ++r) {
      int idx = tid + 512 * r;
      sxh[idx] = f2bf(Xb[idx]);
    }
  }
  __syncthreads();

  // alpha[m] = softmax_m( sum_t X[b,t,m] * eAw[256+t] )  (h/c terms cancel)
  float sval = 0.f;
  if (tid < 128) {
    #pragma unroll 4
    for (int t = 0; t < T_; ++t)
      sval += bf2f(sxh[t * 128 + tid]) * eAw[256 + t];
  }
  float mx = wmax(sval);
  if (lane == 0 && wv < 2) sred[wv] = mx;
  __syncthreads();
  float gmax = fmaxf(sred[0], sred[1]);
  float ee = (tid < 128) ? __expf(sval - gmax) : 0.f;
  float sm = wsum(ee);
  if (lane == 0 && wv < 2) sred[2 + wv] = sm;
  __syncthreads();
  if (tid < 128) {
    su[tid] = ee * rcpf_(sred[2] + sred[3]);
    sh[tid] = 0.f;
    sc[tid] = 0.f;
  }
  __syncthreads();
  // fold alpha into X  ->  x_tilde
  #pragma unroll
  for (int r = 0; r < 25; ++r) {
    int idx = tid + 512 * r;
    sxh[idx] = f2bf(bf2f(sxh[idx]) * su[idx & 127]);
  }

  // encoder weights -> registers: Whh row (fp32), Wih row (bf16 pairs)
  float wa[128];
  u32   wpk[64];
  {
    const float4* wr = (const float4*)(eWhh + (size_t)tid * 128);
    #pragma unroll
    for (int i = 0; i < 32; ++i) {
      float4 v = wr[i];
      wa[4*i+0] = v.x; wa[4*i+1] = v.y; wa[4*i+2] = v.z; wa[4*i+3] = v.w;
    }
    const float4* wi = (const float4*)(eWih + (size_t)tid * 128);
    #pragma unroll
    for (int i = 0; i < 32; ++i) {
      float4 v = wi[i];
      wpk[2*i+0] = pk2(v.x, v.y);
      wpk[2*i+1] = pk2(v.z, v.w);
    }
  }
  float biasg = ebih[tid] + ebhh[tid];
  (void)eAb; // cancels in softmax
  __syncthreads();

  // ================= encoder recurrence =================
  for (int t = 0; t < T_; ++t) {
    float g = biasg;
    {
      const float4* h4 = (const float4*)sh;
      #pragma unroll
      for (int k = 0; k < 32; ++k) {
        float4 hv = h4[k];
        g += wa[4*k+0]*hv.x + wa[4*k+1]*hv.y + wa[4*k+2]*hv.z + wa[4*k+3]*hv.w;
      }
    }
    {
      const uint4* xr = (const uint4*)(sxh + t * 128);
      #pragma unroll
      for (int k = 0; k < 16; ++k) {
        uint4 xp = xr[k];
        float xl, xh, wl, wh;
        unpk(xp.x, xl, xh); unpk(wpk[4*k+0], wl, wh); g += wl*xl + wh*xh;
        unpk(xp.y, xl, xh); unpk(wpk[4*k+1], wl, wh); g += wl*xl + wh*xh;
        unpk(xp.z, xl, xh); unpk(wpk[4*k+2], wl, wh); g += wl*xl + wh*xh;
        unpk(xp.w, xl, xh); unpk(wpk[4*k+3], wl, wh); g += wl*xl + wh*xh;
      }
    }
    sg[tid] = g;
    __syncthreads();
    if (tid < 128) {
      float gi = sigm(sg[tid]);
      float gf = sigm(sg[tid + 128]);
      float gg = tanh_(sg[tid + 256]);
      float go = sigm(sg[tid + 384]);
      float c  = gf * sc[tid] + gi * gg;
      sc[tid]  = c;
      float h  = go * tanh_(c);
      sh[tid]  = h;
      sxe[t * 128 + tid] = f2bf(h);
    }
    __syncthreads();
  }

  // ================= decoder prologue =================
  // E1[t][h] = sum_k Xe[t][k] * dW1[h][256+k] + db1[h]  -> sxh (reuse)
  {
    float acc[25];
    #pragma unroll
    for (int i = 0; i < 25; ++i) acc[i] = 0.f;
    const float* w1x = dW1 + (size_t)hh * 384 + 256;
    for (int kb = 0; kb < 4; ++kb) {
      float wt[32];
      {
        const float4* w4 = (const float4*)(w1x + kb * 32);
        #pragma unroll
        for (int i = 0; i < 8; ++i) {
          float4 v = w4[i];
          wt[4*i+0] = v.x; wt[4*i+1] = v.y; wt[4*i+2] = v.z; wt[4*i+3] = v.w;
        }
      }
      #pragma unroll
      for (int i = 0; i < 25; ++i) {
        const uint4* xr = (const uint4*)(sxe + (qq * 25 + i) * 128 + kb * 32);
        float a = 0.f;
        #pragma unroll
        for (int k4 = 0; k4 < 4; ++k4) {
          uint4 xp = xr[k4];
          float l0,h0,l1,h1,l2,h2,l3,h3;
          unpk(xp.x, l0, h0); unpk(xp.y, l1, h1);
          unpk(xp.z, l2, h2); unpk(xp.w, l3, h3);
          a += wt[8*k4+0]*l0 + wt[8*k4+1]*h0
             + wt[8*k4+2]*l1 + wt[8*k4+3]*h1
             + wt[8*k4+4]*l2 + wt[8*k4+5]*h2
             + wt[8*k4+6]*l3 + wt[8*k4+7]*h3;
        }
        acc[i] += a;
      }
    }
    float b1v = db1[hh];
    #pragma unroll
    for (int i = 0; i < 25; ++i)
      sxh[(qq * 25 + i) * 128 + hh] = f2bf(acc[i] + b1v);
  }

  // decoder weights -> same register arrays (forces reuse):
  // wa = dWhh row j (fp32); wpk[0:16] = W1d quarter-row, wpk[16:32] = W1c quarter-row (bf16 pairs)
  {
    const float4* wr = (const float4*)(dWhh + (size_t)tid * 128);
    #pragma unroll
    for (int i = 0; i < 32; ++i) {
      float4 v = wr[i];
      wa[4*i+0] = v.x; wa[4*i+1] = v.y; wa[4*i+2] = v.z; wa[4*i+3] = v.w;
    }
    const float* w1d = dW1 + (size_t)hh * 384 + qq * 32;
    const float* w1c = w1d + 128;
    #pragma unroll
    for (int i = 0; i < 16; ++i) wpk[i]      = pk2(w1d[2*i], w1d[2*i+1]);
    #pragma unroll
    for (int i = 0; i < 16; ++i) wpk[16 + i] = pk2(w1c[2*i], w1c[2*i+1]);
  }
  float biasD = dbih[tid] + dbhh[tid];
  float wihj  = dWih[tid];
  float w2a   = dW2[lane];
  float w2b   = dW2[lane + 64];
  float b2v   = db2[0];
  float fcbv  = fcb[0];
  float fcwv  = (tid < 128) ? fcW[tid] : 0.f;
  if (tid < 128) { sh[tid] = 0.f; sc[tid] = 0.f; }  // d0, c0
  __syncthreads();

  // ================= decoder recurrence =================
  for (int step = 0; step < T_; ++step) {
    // S0: u partials: u[h] = sum_p W1d[h,p]*d[p] + W1c[h,p]*c[p]  (split-K over qq)
    {
      float pu = 0.f;
      const float2* d2 = ((const float2*)sh) + 16 * qq;
      const float2* c2 = ((const float2*)sc) + 16 * qq;
      #pragma unroll
      for (int i = 0; i < 16; ++i) {
        float wl, wh;
        float2 dv = d2[i];
        unpk(wpk[i], wl, wh);      pu += wl * dv.x + wh * dv.y;
        float2 cv = c2[i];
        unpk(wpk[16 + i], wl, wh); pu += wl * cv.x + wh * cv.y;
      }
      spart[tid] = pu;
    }
    __syncthreads();
    // S1: reduce u
    if (tid < 128)
      su[tid] = spart[tid] + spart[tid + 128] + spart[tid + 256] + spart[tid + 384];
    __syncthreads();
    // S2: scores: score[t] = sum_h w2[h]*tanh(E1[t,h]+u[h]) + b2
    {
      float ul = su[lane], uh = su[lane + 64];
      for (int t = wv; t < T_; t += 8) {
        float v = w2a * tanh_(bf2f(sxh[t * 128 + lane]) + ul)
                + w2b * tanh_(bf2f(sxh[t * 128 + 64 + lane]) + uh);
        v = wsum(v);
        if (lane == 0) sscore[t] = v + b2v;
      }
    }
    __syncthreads();
    // S3: softmax over t (wave 0)
    if (wv == 0) {
      float s0 = sscore[lane];
      float s1 = (lane < 36) ? sscore[lane + 64] : -3.0e38f;
      float m  = wmax(fmaxf(s0, s1));
      float e0 = __expf(s0 - m);
      float e1 = (lane < 36) ? __expf(s1 - m) : 0.f;
      float s  = wsum(e0 + e1);
      float iv = rcpf_(s);
      sscore[lane] = e0 * iv;
      if (lane < 36) sscore[lane + 64] = e1 * iv;
    }
    __syncthreads();
    // S4: ctx partials: ctx[h] = sum_t beta[t]*Xe[t,h]  (split over qq's t-range)
    {
      float pc = 0.f;
      #pragma unroll
      for (int i = 0; i < 25; ++i) {
        int t = qq * 25 + i;
        pc += sscore[t] * bf2f(sxe[t * 128 + hh]);
      }
      spart[tid] = pc;
    }
    __syncthreads();
    // S5: ctx final + y_tilde partial
    {
      float v = 0.f;
      if (tid < 128) {
        float cx = spart[tid] + spart[tid + 128] + spart[tid + 256] + spart[tid + 384];
        sctx[tid] = cx;
        v = fcwv * cx;
      }
      v = wsum(v);
      if (lane == 0 && wv < 2) sred[wv] = v;
    }
    __syncthreads();
    // S6: gates: g[j] = biasD + Wih[j]*y + sum_k Whh[j,k]*d[k]
    {
      float yt = sred[0] + sred[1] + fcbv;
      float g  = biasD + wihj * yt;
      const float4* h4 = (const float4*)sh;
      #pragma unroll
      for (int k = 0; k < 32; ++k) {
        float4 hv = h4[k];
        g += wa[4*k+0]*hv.x + wa[4*k+1]*hv.y + wa[4*k+2]*hv.z + wa[4*k+3]*hv.w;
      }
      sg[tid] = g;
    }
    __syncthreads();
    // S7: pointwise LSTM
    if (tid < 128) {
      float gi = sigm(sg[tid]);
      float gf = sigm(sg[tid + 128]);
      float gg = tanh_(sg[tid + 256]);
      float go = sigm(sg[tid + 384]);
      float c  = gf * sc[tid] + gi * gg;
      sc[tid]  = c;
      sh[tid]  = go * tanh_(c);
    }
    __syncthreads();
  }

  // ================= head: out = [d, ctx] @ fcfW^T + fcfb =================
  if (tid < C_) {
    float acc = fcfb[tid];
    const float* w = fcfW + (size_t)tid * 256;
    #pragma unroll 8
    for (int k = 0; k < 128; ++k)
      acc += w[k] * sh[k] + w[128 + k] * sctx[k];
    out[(size_t)b * C_ + tid] = acc;
  }
}

extern "C" void kernel_launch(void* const* d_in, const int* in_sizes, int n_in,
                              void* d_out, int out_size, void* d_ws, size_t ws_size,
                              hipStream_t stream) {
  (void)n_in; (void)out_size; (void)d_ws; (void)ws_size;
  const float* X    = (const float*)d_in[0];
  const float* eWih = (const float*)d_in[1];
  const float* eWhh = (const float*)d_in[2];
  const float* ebih = (const float*)d_in[3];
  const float* ebhh = (const float*)d_in[4];
  const float* eAw  = (const float*)d_in[5];
  const float* eAb  = (const float*)d_in[6];
  const float* dW1  = (const float*)d_in[7];
  const float* db1  = (const float*)d_in[8];
  const float* dW2  = (const float*)d_in[9];
  const float* db2  = (const float*)d_in[10];
  const float* dWih = (const float*)d_in[11];
  const float* dWhh = (const float*)d_in[12];
  const float* dbih = (const float*)d_in[13];
  const float* dbhh = (const float*)d_in[14];
  const float* fcW  = (const float*)d_in[15];
  const float* fcb  = (const float*)d_in[16];
  const float* fcfW = (const float*)d_in[17];
  const float* fcfb = (const float*)d_in[18];
  float* out = (float*)d_out;

  const int B = in_sizes[0] / (T_ * 128);
  darnn_fused<<<dim3(B), dim3(512), 0, stream>>>(
      X, eWih, eWhh, ebih, ebhh, eAw, eAb,
      dW1, db1, dW2, db2, dWih, dWhh, dbih, dbhh,
      fcW, fcb, fcfW, fcfb, out);
}